// Round 5
// baseline (696.877 us; speedup 1.0000x reference)
//
#include <hip/hip_runtime.h>
#include <cmath>
#include <cstdint>

// ---------------------------------------------------------------------------
// SeparateHiddenGCAEEncoder: 4 chained GCN convs, P = D^-1/2 (A+I) D^-1/2.
// Round 13: visibility + overlap.
//  - gather_fused split into two node-range halves (diagnostic: un-saturates
//    the profiler top-5 so the hidden #2 kernel becomes visible; zero cost)
//  - fill ∥ conv1-GEMM merged into one block-partitioned launch (independent
//    work, disjoint bottlenecks: scatter/random-L2 vs streaming+MFMA)
//  - everything else unchanged (gather sweeps at 3.65 TB/s fabric ceiling,
//    traffic at structural floor)
// ---------------------------------------------------------------------------

typedef _Float16 f16;
typedef _Float16 f16x8 __attribute__((ext_vector_type(8)));
typedef _Float16 f16x4 __attribute__((ext_vector_type(4)));
typedef float f32x4 __attribute__((ext_vector_type(4)));
typedef unsigned int u32x4 __attribute__((ext_vector_type(4)));
typedef unsigned int u32x2 __attribute__((ext_vector_type(2)));

constexpr int PERSIST_BLOCKS = 2048;  // 8 blocks/CU x 256 CU resident capacity

// ---------------- weight prep helper ----------------------------------------
// Fragment order for mfma_f32_16x16x32_f16 B operand: value W[k][m] lives at
//   ((k/32)*(M/16) + m/16)*512 + lane*8 + (k&7), lane = ((k>>3)&3)*16 + (m&15)
__device__ inline void wprep_one(const float* __restrict__ W, f16* __restrict__ hi,
                                 f16* __restrict__ lo, int M, int idx) {
    int k = idx / M, m = idx % M;
    float w = W[idx];
    f16 h = (f16)w;
    int f = ((k >> 5) * (M >> 4) + (m >> 4)) * 512 + (((k >> 3) & 3) << 7) + ((m & 15) << 3) + (k & 7);
    hi[f] = h;
    lo[f] = (f16)(w - (float)h);
}

// ---------------- fused prep: count+rank ∥ weight prep ∥ cond convert -------
__global__ void prep_graph_kernel(const int* __restrict__ dst, int* __restrict__ count,
                                  int* __restrict__ rank, int E, int cb,
                                  const float* __restrict__ W1, f16* h1, f16* l1,
                                  const float* __restrict__ W2, f16* h2, f16* l2,
                                  const float* __restrict__ W3, f16* h3, f16* l3,
                                  const float* __restrict__ W4, f16* h4, f16* l4,
                                  const float* __restrict__ cond, f16* __restrict__ XL, int N) {
    int b = blockIdx.x;
    int t = threadIdx.x;
    if (b < cb) {
        int e = b * 256 + t;
        if (e < E) rank[e] = atomicAdd(&count[dst[e]], 1);
    } else if (b < cb + 128) {
        wprep_one(W1, h1, l1, 128, (b - cb) * 256 + t);            // 256x128
    } else if (b < cb + 160) {
        wprep_one(W2, h2, l2, 128, (b - cb - 128) * 256 + t);      // 64x128
    } else if (b < cb + 288) {
        wprep_one(W3, h3, l3, 128, (b - cb - 160) * 256 + t);      // 256x128
    } else if (b < cb + 320) {
        wprep_one(W4, h4, l4, 64, (b - cb - 288) * 256 + t);       // 128x64
    } else {
        int i = (b - cb - 320) * 256 + t;                          // quad index
        if (i < N * 16) {
            int node = i >> 4, q = i & 15;
            float4 v = ((const float4*)cond)[i];
            union { f16 h[4]; uint2 u; } p;
            p.h[0] = (f16)v.x; p.h[1] = (f16)v.y; p.h[2] = (f16)v.z; p.h[3] = (f16)v.w;
            *(uint2*)(XL + (size_t)node * 192 + 128 + q * 4) = p.u;
        }
    }
}

constexpr int SCAN_VPT = 8;
constexpr int SCAN_TILE = 256 * SCAN_VPT;  // 2048

// partial sums + dinv (count is loaded here anyway)
__global__ __launch_bounds__(256) void scan_partial_kernel(const int* __restrict__ count,
                                                           float* __restrict__ dinv,
                                                           int* __restrict__ blocksums, int N) {
    __shared__ int red[256];
    const int t = threadIdx.x;
    int base = blockIdx.x * SCAN_TILE + t * SCAN_VPT;
    int s = 0;
#pragma unroll
    for (int i = 0; i < SCAN_VPT; ++i) {
        int idx = base + i;
        if (idx < N) {
            int c = count[idx];
            dinv[idx] = rsqrtf((float)(c + 1));  // +1 self loop
            s += c;
        }
    }
    red[t] = s;
    __syncthreads();
    for (int off = 128; off > 0; off >>= 1) {
        if (t < off) red[t] += red[t + off];
        __syncthreads();
    }
    if (t == 0) blocksums[blockIdx.x] = red[0];
}

// final scan; block-sum exclusive scan (<=64 blocks) inlined per block
__global__ __launch_bounds__(256) void scan_final_kernel(const int* __restrict__ count,
                                                         const int* __restrict__ blocksums,
                                                         int* __restrict__ row_ptr, int N, int nb) {
    __shared__ int red[256];
    __shared__ int bs[64];
    const int t = threadIdx.x;
    if (t < 64) bs[t] = (t < nb) ? blocksums[t] : 0;
    __syncthreads();
    for (int off = 1; off < 64; off <<= 1) {
        int u = (t < 64 && t >= off) ? bs[t - off] : 0;
        __syncthreads();
        if (t < 64) bs[t] += u;
        __syncthreads();
    }
    const int myBase = (blockIdx.x > 0) ? bs[blockIdx.x - 1] : 0;

    int base = blockIdx.x * SCAN_TILE + t * SCAN_VPT;
    int vals[SCAN_VPT];
    int s = 0;
#pragma unroll
    for (int i = 0; i < SCAN_VPT; ++i) {
        int idx = base + i;
        vals[i] = (idx < N) ? count[idx] : 0;
        s += vals[i];
    }
    red[t] = s;
    __syncthreads();
    for (int off = 1; off < 256; off <<= 1) {
        int u = (t >= off) ? red[t - off] : 0;
        __syncthreads();
        red[t] += u;
        __syncthreads();
    }
    int run = red[t] - s + myBase;
#pragma unroll
    for (int i = 0; i < SCAN_VPT; ++i) {
        int idx = base + i;
        if (idx < N) {
            row_ptr[idx] = run;
            run += vals[i];
            if (idx == N - 1) row_ptr[N] = run;
        }
    }
}

// ---------------- fill body (device) ----------------------------------------
__device__ inline void fill_body(int b, const int* __restrict__ src, const int* __restrict__ dst,
                                 const int* __restrict__ rank, const float* __restrict__ dinv,
                                 const int* __restrict__ row_ptr, long long* __restrict__ csr,
                                 int E) {
    int e = b * 256 + threadIdx.x;
    if (e >= E) return;
    int s = src[e];
    int d = dst[e];
    int pos = row_ptr[d] + rank[e];
    float nrm = dinv[s] * dinv[d];
    long long v = ((long long)(unsigned)__float_as_int(nrm) << 32) | (unsigned)s;
    __builtin_nontemporal_store(v, csr + pos);
}

// ---------------- no-LDS direct-fragment MFMA GEMM body (conv1) -------------
template <int K, int M, bool X_IS_HALF>
__device__ inline void gemm_direct_body(
    int bid, const void* __restrict__ Xv, const f16* __restrict__ WFh,
    const f16* __restrict__ WFl, f16* __restrict__ out,
    int ld, int colOff, int ldx, int N) {
    constexpr int BM = 128;
    constexpr int SW = M / 4;
    constexpr int CT = SW / 16;
    constexpr int RT = BM / 16;
    constexpr int KS = K / 32;
    constexpr int MT = M / 16;

    const int tid = threadIdx.x;
    const int lane = tid & 63;
    const int wv = tid >> 6;
    const int m16 = lane & 15;
    const int quad = lane >> 4;
    const int row0 = bid * BM;

    int xr[RT];
#pragma unroll
    for (int rt = 0; rt < RT; ++rt) {
        int r = row0 + rt * 16 + m16;
        xr[rt] = r < N ? r : N - 1;
    }

    f32x4 acc[RT][CT];
#pragma unroll
    for (int rt = 0; rt < RT; ++rt)
#pragma unroll
        for (int ct = 0; ct < CT; ++ct) acc[rt][ct] = (f32x4){0.f, 0.f, 0.f, 0.f};

    for (int ks = 0; ks < KS; ++ks) {
        const int k0 = ks * 32;
        f16x8 bh[CT], bl[CT];
#pragma unroll
        for (int ct = 0; ct < CT; ++ct) {
            const int fb = ((ks * MT + wv * CT + ct) << 9) + lane * 8;
            bh[ct] = *(const f16x8*)(WFh + fb);
            bl[ct] = *(const f16x8*)(WFl + fb);
        }
#pragma unroll
        for (int rt = 0; rt < RT; ++rt) {
            f16x8 a;
            if (X_IS_HALF) {
                a = *(const f16x8*)((const f16*)Xv + (size_t)xr[rt] * ldx + k0 + quad * 8);
            } else {
                const float* xp = (const float*)Xv + (size_t)xr[rt] * ldx + k0 + quad * 8;
                f32x4 v0 = *(const f32x4*)xp;
                f32x4 v1 = *(const f32x4*)(xp + 4);
                a[0] = (f16)v0[0]; a[1] = (f16)v0[1]; a[2] = (f16)v0[2]; a[3] = (f16)v0[3];
                a[4] = (f16)v1[0]; a[5] = (f16)v1[1]; a[6] = (f16)v1[2]; a[7] = (f16)v1[3];
            }
#pragma unroll
            for (int ct = 0; ct < CT; ++ct) {
                acc[rt][ct] = __builtin_amdgcn_mfma_f32_16x16x32_f16(a, bh[ct], acc[rt][ct], 0, 0, 0);
                acc[rt][ct] = __builtin_amdgcn_mfma_f32_16x16x32_f16(a, bl[ct], acc[rt][ct], 0, 0, 0);
            }
        }
    }

#pragma unroll
    for (int rt = 0; rt < RT; ++rt) {
#pragma unroll
        for (int r = 0; r < 4; ++r) {
            int row = row0 + rt * 16 + quad * 4 + r;
            if (row < N) {
                f16* op = out + (size_t)row * ld + colOff + wv * SW + m16;
#pragma unroll
                for (int ct = 0; ct < CT; ++ct) op[ct * 16] = (f16)acc[rt][ct][r];
            }
        }
    }
}

// ---------------- merged: conv1 GEMM ∥ CSR fill ------------------------------
// blocks [0, gemmBlocks): conv1 feature@W1 -> XL[:,0:128]
// blocks [gemmBlocks, gemmBlocks+fillBlocks): csr fill
__global__ __launch_bounds__(256) void fill_conv1_kernel(
    const float* __restrict__ feature, const f16* __restrict__ W1h,
    const f16* __restrict__ W1l, f16* __restrict__ XL, int N, int gemmBlocks,
    const int* __restrict__ src, const int* __restrict__ dst,
    const int* __restrict__ rank, const float* __restrict__ dinv,
    const int* __restrict__ row_ptr, long long* __restrict__ csr, int E) {
    int b = blockIdx.x;
    if (b < gemmBlocks) {
        gemm_direct_body<256, 128, false>(b, feature, W1h, W1l, XL, 192, 0, 256, N);
    } else {
        fill_body(b - gemmBlocks, src, dst, rank, dinv, row_ptr, csr, E);
    }
}

// ---------------- fused conv2+conv3 GEMM ------------------------------------
// Bh rows: [f2h (128) | cprop (64) | unused], ld 256.
// step1: c2h = tanh(cprop @ W2 + b2) -> LDS tile [128][136]
// step2: out = [f2h | c2h] @ W3 -> outXL [N][128] (no bias; applied post-P)
__global__ __launch_bounds__(256) void gemm_conv23_kernel(
    const f16* __restrict__ Bh, const f16* __restrict__ W2h, const f16* __restrict__ W2l,
    const float* __restrict__ b2, const f16* __restrict__ W3h, const f16* __restrict__ W3l,
    f16* __restrict__ outXL, int N) {
    constexpr int RT = 8, CT = 2, LP = 136;
    __shared__ f16 c2s[128 * LP];

    const int tid = threadIdx.x;
    const int lane = tid & 63;
    const int wv = tid >> 6;
    const int m16 = lane & 15;
    const int quad = lane >> 4;
    const int row0 = blockIdx.x * 128;

    int xr[RT];
#pragma unroll
    for (int rt = 0; rt < RT; ++rt) {
        int r = row0 + rt * 16 + m16;
        xr[rt] = r < N ? r : N - 1;
    }

    // ---- step 1: c2h tile ----
    {
        f32x4 acc2[RT][CT];
#pragma unroll
        for (int rt = 0; rt < RT; ++rt)
#pragma unroll
            for (int ct = 0; ct < CT; ++ct) acc2[rt][ct] = (f32x4){0.f, 0.f, 0.f, 0.f};
#pragma unroll
        for (int ks = 0; ks < 2; ++ks) {
            f16x8 bh[CT], bl[CT];
#pragma unroll
            for (int ct = 0; ct < CT; ++ct) {
                const int fb = ((ks * 8 + wv * CT + ct) << 9) + lane * 8;
                bh[ct] = *(const f16x8*)(W2h + fb);
                bl[ct] = *(const f16x8*)(W2l + fb);
            }
#pragma unroll
            for (int rt = 0; rt < RT; ++rt) {
                f16x8 a = *(const f16x8*)(Bh + (size_t)xr[rt] * 256 + 128 + ks * 32 + quad * 8);
#pragma unroll
                for (int ct = 0; ct < CT; ++ct) {
                    acc2[rt][ct] = __builtin_amdgcn_mfma_f32_16x16x32_f16(a, bh[ct], acc2[rt][ct], 0, 0, 0);
                    acc2[rt][ct] = __builtin_amdgcn_mfma_f32_16x16x32_f16(a, bl[ct], acc2[rt][ct], 0, 0, 0);
                }
            }
        }
        float b2r[CT];
#pragma unroll
        for (int ct = 0; ct < CT; ++ct) b2r[ct] = b2[wv * 32 + ct * 16 + m16];
#pragma unroll
        for (int rt = 0; rt < RT; ++rt)
#pragma unroll
            for (int r = 0; r < 4; ++r) {
                int row = rt * 16 + quad * 4 + r;
#pragma unroll
                for (int ct = 0; ct < CT; ++ct)
                    c2s[row * LP + wv * 32 + ct * 16 + m16] = (f16)tanhf(acc2[rt][ct][r] + b2r[ct]);
            }
    }
    __syncthreads();

    // ---- step 2: [f2h | c2h] @ W3 ----
    f32x4 acc3[RT][CT];
#pragma unroll
    for (int rt = 0; rt < RT; ++rt)
#pragma unroll
        for (int ct = 0; ct < CT; ++ct) acc3[rt][ct] = (f32x4){0.f, 0.f, 0.f, 0.f};
#pragma unroll
    for (int ks = 0; ks < 8; ++ks) {
        f16x8 bh[CT], bl[CT];
#pragma unroll
        for (int ct = 0; ct < CT; ++ct) {
            const int fb = ((ks * 8 + wv * CT + ct) << 9) + lane * 8;
            bh[ct] = *(const f16x8*)(W3h + fb);
            bl[ct] = *(const f16x8*)(W3l + fb);
        }
#pragma unroll
        for (int rt = 0; rt < RT; ++rt) {
            f16x8 a;
            if (ks < 4) {
                a = *(const f16x8*)(Bh + (size_t)xr[rt] * 256 + ks * 32 + quad * 8);
            } else {
                a = *(const f16x8*)(&c2s[(rt * 16 + m16) * LP + (ks - 4) * 32 + quad * 8]);
            }
#pragma unroll
            for (int ct = 0; ct < CT; ++ct) {
                acc3[rt][ct] = __builtin_amdgcn_mfma_f32_16x16x32_f16(a, bh[ct], acc3[rt][ct], 0, 0, 0);
                acc3[rt][ct] = __builtin_amdgcn_mfma_f32_16x16x32_f16(a, bl[ct], acc3[rt][ct], 0, 0, 0);
            }
        }
    }

#pragma unroll
    for (int rt = 0; rt < RT; ++rt)
#pragma unroll
        for (int r = 0; r < 4; ++r) {
            int row = row0 + rt * 16 + quad * 4 + r;
            if (row < N) {
                f16* op = outXL + (size_t)row * 128 + wv * 32 + m16;
#pragma unroll
                for (int ct = 0; ct < CT; ++ct) op[ct * 16] = (f16)acc3[rt][ct][r];
            }
        }
}

// ---------------- generic f16 gather (persistent, conv4 final) --------------
template <int M, bool TANH, bool HAS_BIAS, bool OUT_F32>
__global__ __launch_bounds__(256) void gather_h_kernel(
    const f16* __restrict__ xl, const float* __restrict__ b,
    const float* __restrict__ dinv, const int* __restrict__ row_ptr,
    const long long* __restrict__ csr, void* __restrict__ outv,
    int ld, int colOff, int N) {
    constexpr int TPN = M / 8;
    const int nch = (N * TPN + 255) / 256;
    for (int c = blockIdx.x; c < nch; c += gridDim.x) {
        int gid = c * 256 + threadIdx.x;
        int node = gid / TPN;
        int t = gid % TPN;
        if (node >= N) continue;

        float di = dinv[node];
        float self = di * di;
        f16x8 x = *(const f16x8*)(xl + (size_t)node * M + t * 8);
        float acc[8];
#pragma unroll
        for (int j = 0; j < 8; ++j) acc[j] = (float)x[j] * self;
        if (HAS_BIAS) {
            float4 b0 = *(const float4*)(b + t * 8);
            float4 b1 = *(const float4*)(b + t * 8 + 4);
            acc[0] += b0.x; acc[1] += b0.y; acc[2] += b0.z; acc[3] += b0.w;
            acc[4] += b1.x; acc[5] += b1.y; acc[6] += b1.z; acc[7] += b1.w;
        }

        int p = row_ptr[node];
        const int p1 = row_ptr[node + 1];
        const int last = p1 - 1;
        long long e0 = 0, e1 = 0, e2 = 0, e3 = 0;
        if (p < p1) {
            e0 = __builtin_nontemporal_load(csr + p);
            e1 = __builtin_nontemporal_load(csr + (p + 1 < p1 ? p + 1 : last));
            e2 = __builtin_nontemporal_load(csr + (p + 2 < p1 ? p + 2 : last));
            e3 = __builtin_nontemporal_load(csr + (p + 3 < p1 ? p + 3 : last));
        }
        while (p < p1) {
            const long long c0 = e0, c1 = e1, c2 = e2, c3 = e3;
            const int pn = p + 4;
            if (pn < p1) {
                e0 = __builtin_nontemporal_load(csr + pn);
                e1 = __builtin_nontemporal_load(csr + (pn + 1 < p1 ? pn + 1 : last));
                e2 = __builtin_nontemporal_load(csr + (pn + 2 < p1 ? pn + 2 : last));
                e3 = __builtin_nontemporal_load(csr + (pn + 3 < p1 ? pn + 3 : last));
            }
            int s0 = (int)c0, s1 = (int)c1, s2 = (int)c2, s3 = (int)c3;
            float n0 = __int_as_float((int)(c0 >> 32));
            float n1 = (p + 1 < p1) ? __int_as_float((int)(c1 >> 32)) : 0.f;
            float n2 = (p + 2 < p1) ? __int_as_float((int)(c2 >> 32)) : 0.f;
            float n3 = (p + 3 < p1) ? __int_as_float((int)(c3 >> 32)) : 0.f;
            f16x8 v0 = *(const f16x8*)(xl + (size_t)s0 * M + t * 8);
            f16x8 v1 = *(const f16x8*)(xl + (size_t)s1 * M + t * 8);
            f16x8 v2 = *(const f16x8*)(xl + (size_t)s2 * M + t * 8);
            f16x8 v3 = *(const f16x8*)(xl + (size_t)s3 * M + t * 8);
#pragma unroll
            for (int j = 0; j < 8; ++j)
                acc[j] += ((float)v0[j] * n0 + (float)v1[j] * n1) +
                          ((float)v2[j] * n2 + (float)v3[j] * n3);
            p = pn;
        }

        if (TANH) {
#pragma unroll
            for (int j = 0; j < 8; ++j) acc[j] = tanhf(acc[j]);
        }

        if (OUT_F32) {
            float* op = (float*)outv + (size_t)node * ld + colOff + t * 8;
            f32x4 o0 = {acc[0], acc[1], acc[2], acc[3]};
            f32x4 o1 = {acc[4], acc[5], acc[6], acc[7]};
            __builtin_nontemporal_store(o0, (f32x4*)op);
            __builtin_nontemporal_store(o1, (f32x4*)(op + 4));
        } else {
            union { f16 h[8]; u32x4 u; } o;
#pragma unroll
            for (int j = 0; j < 8; ++j) o.h[j] = (f16)acc[j];
            __builtin_nontemporal_store(o.u, (u32x4*)((f16*)outv + (size_t)node * ld + colOff + t * 8));
        }
    }
}

// ---------------- fused conv1/conv2 gather (persistent, node range) ---------
__global__ __launch_bounds__(256) void gather_fused_kernel(
    const f16* __restrict__ XL, const float* __restrict__ bA,
    const float* __restrict__ dinv, const int* __restrict__ row_ptr,
    const long long* __restrict__ csr, f16* __restrict__ out, int n0, int n1) {
    const int nch = ((n1 - n0) * 16 + 255) / 256;
    const int t = threadIdx.x & 15;
    for (int c = blockIdx.x; c < nch; c += gridDim.x) {
        int node = n0 + ((c * 256 + threadIdx.x) >> 4);
        if (node >= n1) continue;

        float di = dinv[node];
        float self = di * di;
        const f16* base = XL + (size_t)node * 192;
        f16x8 xa = *(const f16x8*)(base + t * 8);
        f16x4 xc = *(const f16x4*)(base + 128 + t * 4);
        float accA[8], accC[4];
#pragma unroll
        for (int j = 0; j < 8; ++j) accA[j] = (float)xa[j] * self;
#pragma unroll
        for (int j = 0; j < 4; ++j) accC[j] = (float)xc[j] * self;
        {
            float4 b0 = *(const float4*)(bA + t * 8);
            float4 b1 = *(const float4*)(bA + t * 8 + 4);
            accA[0] += b0.x; accA[1] += b0.y; accA[2] += b0.z; accA[3] += b0.w;
            accA[4] += b1.x; accA[5] += b1.y; accA[6] += b1.z; accA[7] += b1.w;
        }

        int p = row_ptr[node];
        const int p1 = row_ptr[node + 1];
        const int last = p1 - 1;
        long long e0 = 0, e1 = 0, e2 = 0, e3 = 0;
        if (p < p1) {
            e0 = __builtin_nontemporal_load(csr + p);
            e1 = __builtin_nontemporal_load(csr + (p + 1 < p1 ? p + 1 : last));
            e2 = __builtin_nontemporal_load(csr + (p + 2 < p1 ? p + 2 : last));
            e3 = __builtin_nontemporal_load(csr + (p + 3 < p1 ? p + 3 : last));
        }
        while (p < p1) {
            const long long c0 = e0, c1 = e1, c2 = e2, c3 = e3;
            const int pn = p + 4;
            if (pn < p1) {
                e0 = __builtin_nontemporal_load(csr + pn);
                e1 = __builtin_nontemporal_load(csr + (pn + 1 < p1 ? pn + 1 : last));
                e2 = __builtin_nontemporal_load(csr + (pn + 2 < p1 ? pn + 2 : last));
                e3 = __builtin_nontemporal_load(csr + (pn + 3 < p1 ? pn + 3 : last));
            }
            int s0 = (int)c0, s1 = (int)c1, s2 = (int)c2, s3 = (int)c3;
            float n0f = __int_as_float((int)(c0 >> 32));
            float n1f = (p + 1 < p1) ? __int_as_float((int)(c1 >> 32)) : 0.f;
            float n2f = (p + 2 < p1) ? __int_as_float((int)(c2 >> 32)) : 0.f;
            float n3f = (p + 3 < p1) ? __int_as_float((int)(c3 >> 32)) : 0.f;
            const f16* r0 = XL + (size_t)s0 * 192;
            const f16* r1 = XL + (size_t)s1 * 192;
            const f16* r2 = XL + (size_t)s2 * 192;
            const f16* r3 = XL + (size_t)s3 * 192;
            f16x8 a0 = *(const f16x8*)(r0 + t * 8);
            f16x8 a1 = *(const f16x8*)(r1 + t * 8);
            f16x8 a2 = *(const f16x8*)(r2 + t * 8);
            f16x8 a3 = *(const f16x8*)(r3 + t * 8);
            f16x4 q0 = *(const f16x4*)(r0 + 128 + t * 4);
            f16x4 q1 = *(const f16x4*)(r1 + 128 + t * 4);
            f16x4 q2 = *(const f16x4*)(r2 + 128 + t * 4);
            f16x4 q3 = *(const f16x4*)(r3 + 128 + t * 4);
#pragma unroll
            for (int j = 0; j < 8; ++j)
                accA[j] += ((float)a0[j] * n0f + (float)a1[j] * n1f) +
                           ((float)a2[j] * n2f + (float)a3[j] * n3f);
#pragma unroll
            for (int j = 0; j < 4; ++j)
                accC[j] += ((float)q0[j] * n0f + (float)q1[j] * n1f) +
                           ((float)q2[j] * n2f + (float)q3[j] * n3f);
            p = pn;
        }

#pragma unroll
        for (int j = 0; j < 8; ++j) accA[j] = tanhf(accA[j]);

        union { f16 h[8]; u32x4 u; } oa;
#pragma unroll
        for (int j = 0; j < 8; ++j) oa.h[j] = (f16)accA[j];
        __builtin_nontemporal_store(oa.u, (u32x4*)(out + (size_t)node * 256 + t * 8));
        union { f16 h[4]; u32x2 u; } oc;
#pragma unroll
        for (int j = 0; j < 4; ++j) oc.h[j] = (f16)accC[j];
        __builtin_nontemporal_store(oc.u, (u32x2*)(out + (size_t)node * 256 + 128 + t * 4));
    }
}

// ---------------- fused conv3 gather + conv4 GEMM (persistent) --------------
__global__ __launch_bounds__(256) void gather34_kernel(
    const f16* __restrict__ xl, const float* __restrict__ b,
    const float* __restrict__ dinv, const int* __restrict__ row_ptr,
    const long long* __restrict__ csr, const f16* __restrict__ W4h,
    const f16* __restrict__ W4l, f16* __restrict__ zpre, int N) {
    constexpr int LP = 136;
    __shared__ f16 h2s[16 * LP];
    const int tid = threadIdx.x;
    const int nloc = tid >> 4;
    const int t = tid & 15;
    const int lane = tid & 63;
    const int wv = tid >> 6;
    const int m16 = lane & 15;
    const int quad = lane >> 4;
    const int nch = (N + 15) / 16;

    for (int c = blockIdx.x; c < nch; c += gridDim.x) {
        const int node = c * 16 + nloc;
        const bool active = node < N;

        float acc[8];
        if (active) {
            float di = dinv[node];
            float self = di * di;
            f16x8 x = *(const f16x8*)(xl + (size_t)node * 128 + t * 8);
#pragma unroll
            for (int j = 0; j < 8; ++j) acc[j] = (float)x[j] * self;
            {
                float4 b0 = *(const float4*)(b + t * 8);
                float4 b1 = *(const float4*)(b + t * 8 + 4);
                acc[0] += b0.x; acc[1] += b0.y; acc[2] += b0.z; acc[3] += b0.w;
                acc[4] += b1.x; acc[5] += b1.y; acc[6] += b1.z; acc[7] += b1.w;
            }

            int p = row_ptr[node];
            const int p1 = row_ptr[node + 1];
            const int last = p1 - 1;
            long long e0 = 0, e1 = 0, e2 = 0, e3 = 0;
            if (p < p1) {
                e0 = __builtin_nontemporal_load(csr + p);
                e1 = __builtin_nontemporal_load(csr + (p + 1 < p1 ? p + 1 : last));
                e2 = __builtin_nontemporal_load(csr + (p + 2 < p1 ? p + 2 : last));
                e3 = __builtin_nontemporal_load(csr + (p + 3 < p1 ? p + 3 : last));
            }
            while (p < p1) {
                const long long c0 = e0, c1 = e1, c2 = e2, c3 = e3;
                const int pn = p + 4;
                if (pn < p1) {
                    e0 = __builtin_nontemporal_load(csr + pn);
                    e1 = __builtin_nontemporal_load(csr + (pn + 1 < p1 ? pn + 1 : last));
                    e2 = __builtin_nontemporal_load(csr + (pn + 2 < p1 ? pn + 2 : last));
                    e3 = __builtin_nontemporal_load(csr + (pn + 3 < p1 ? pn + 3 : last));
                }
                int s0 = (int)c0, s1 = (int)c1, s2 = (int)c2, s3 = (int)c3;
                float n0 = __int_as_float((int)(c0 >> 32));
                float n1 = (p + 1 < p1) ? __int_as_float((int)(c1 >> 32)) : 0.f;
                float n2 = (p + 2 < p1) ? __int_as_float((int)(c2 >> 32)) : 0.f;
                float n3 = (p + 3 < p1) ? __int_as_float((int)(c3 >> 32)) : 0.f;
                f16x8 v0 = *(const f16x8*)(xl + (size_t)s0 * 128 + t * 8);
                f16x8 v1 = *(const f16x8*)(xl + (size_t)s1 * 128 + t * 8);
                f16x8 v2 = *(const f16x8*)(xl + (size_t)s2 * 128 + t * 8);
                f16x8 v3 = *(const f16x8*)(xl + (size_t)s3 * 128 + t * 8);
#pragma unroll
                for (int j = 0; j < 8; ++j)
                    acc[j] += ((float)v0[j] * n0 + (float)v1[j] * n1) +
                              ((float)v2[j] * n2 + (float)v3[j] * n3);
                p = pn;
            }

            union { f16 h[8]; u32x4 u; } o;
#pragma unroll
            for (int j = 0; j < 8; ++j) o.h[j] = (f16)tanhf(acc[j]);
            *(u32x4*)(&h2s[nloc * LP + t * 8]) = o.u;
        }
        __syncthreads();

        // mini-GEMM: zpre[16][64] = h2s[16][128] @ W4
        f32x4 a4 = (f32x4){0.f, 0.f, 0.f, 0.f};
#pragma unroll
        for (int ks = 0; ks < 4; ++ks) {
            f16x8 av = *(const f16x8*)(&h2s[m16 * LP + ks * 32 + quad * 8]);
            const int fb = ((ks * 4 + wv) << 9) + lane * 8;
            f16x8 bh = *(const f16x8*)(W4h + fb);
            f16x8 bl = *(const f16x8*)(W4l + fb);
            a4 = __builtin_amdgcn_mfma_f32_16x16x32_f16(av, bh, a4, 0, 0, 0);
            a4 = __builtin_amdgcn_mfma_f32_16x16x32_f16(av, bl, a4, 0, 0, 0);
        }
#pragma unroll
        for (int r = 0; r < 4; ++r) {
            int g = c * 16 + quad * 4 + r;
            if (g < N) zpre[(size_t)g * 64 + wv * 16 + m16] = (f16)a4[r];
        }
        __syncthreads();  // protect h2s before next chunk overwrites
    }
}

// ---------------------------------------------------------------------------
extern "C" void kernel_launch(void* const* d_in, const int* in_sizes, int n_in,
                              void* d_out, int out_size, void* d_ws, size_t ws_size,
                              hipStream_t stream) {
    const int FD = 256;

    const float* feature   = (const float*)d_in[0];
    const float* condition = (const float*)d_in[1];
    const int*   edge      = (const int*)d_in[2];
    const float* W_f2h = (const float*)d_in[3];
    const float* b_f2h = (const float*)d_in[4];
    const float* W_c2h = (const float*)d_in[5];
    const float* b_c2h = (const float*)d_in[6];
    const float* W_h2h = (const float*)d_in[7];
    const float* b_h2h = (const float*)d_in[8];
    const float* W_h2l = (const float*)d_in[9];
    const float* b_h2l = (const float*)d_in[10];
    float* out = (float*)d_out;

    const int N = in_sizes[0] / FD;   // 100000
    const int E = in_sizes[2] / 2;    // 1600000
    const int* src = edge;
    const int* dst = edge + E;

    // workspace layout
    float* ws_f   = (float*)d_ws;
    float* dinv   = ws_f;                                // N floats
    int*   count  = (int*)(ws_f + N);                    // N ints
    int*   rowp   = count + N;                           // N+1 ints
    int*   bsums  = rowp + N + 1;                        // 1024 ints
    int*   rank   = bsums + 1024;                        // E ints
    long long* csr = (long long*)(((uintptr_t)(rank + E) + 15) & ~(uintptr_t)15);  // E x 8B
    f16*   XL     = (f16*)(csr + E);                     // N*192 f16 ([xlA|cond]; reused as h@W3)
    f16*   B_h    = XL + (size_t)N * 192;                // N*256 f16 ([f2h|cprop]; reused as zpre)
    f16*   wt1h   = B_h + (size_t)N * 256;               // 128*256
    f16*   wt1l   = wt1h + 128 * 256;
    f16*   wt2h   = wt1l + 128 * 256;                    // 128*64
    f16*   wt2l   = wt2h + 128 * 64;
    f16*   wt3h   = wt2l + 128 * 64;                     // 128*256
    f16*   wt3l   = wt3h + 128 * 256;
    f16*   wt4h   = wt3l + 128 * 256;                    // 64*128
    f16*   wt4l   = wt4h + 64 * 128;

    const int TB = 256;
    dim3 blk(TB);
    const int nScanBlocks = (N + SCAN_TILE - 1) / SCAN_TILE;  // 49 (<=64 required)
    const int countBlocks = (E + TB - 1) / TB;                // 6250
    const int condBlocks  = (N * 16 + TB - 1) / TB;           // 6250
    const int gemm_grid   = (N + 127) / 128;                  // 782

    // --- fused prep: count_rank ∥ wprep ∥ cond convert ---
    hipMemsetAsync(count, 0, (size_t)N * sizeof(int), stream);
    prep_graph_kernel<<<countBlocks + 320 + condBlocks, blk, 0, stream>>>(
        dst, count, rank, E, countBlocks,
        W_f2h, wt1h, wt1l, W_c2h, wt2h, wt2l, W_h2h, wt3h, wt3l, W_h2l, wt4h, wt4l,
        condition, XL, N);

    // --- CSR scan ---
    scan_partial_kernel<<<nScanBlocks, blk, 0, stream>>>(count, dinv, bsums, N);
    scan_final_kernel<<<nScanBlocks, blk, 0, stream>>>(count, bsums, rowp, N, nScanBlocks);

    // --- conv1 GEMM ∥ CSR fill (independent; disjoint bottlenecks) ---
    fill_conv1_kernel<<<gemm_grid + countBlocks, blk, 0, stream>>>(
        feature, wt1h, wt1l, XL, N, gemm_grid,
        src, dst, rank, dinv, rowp, csr, E);

    // --- fused gather conv1+conv2 (two node-range halves; diagnostic split) ---
    const int nHalf = N / 2;
    gather_fused_kernel<<<PERSIST_BLOCKS, blk, 0, stream>>>(
        XL, b_f2h, dinv, rowp, csr, B_h, 0, nHalf);
    gather_fused_kernel<<<PERSIST_BLOCKS, blk, 0, stream>>>(
        XL, b_f2h, dinv, rowp, csr, B_h, nHalf, N);

    // --- fused conv2+conv3 GEMM: [f2h | tanh(cprop@W2+b2)] @ W3 -> XL ---
    gemm_conv23_kernel<<<gemm_grid, blk, 0, stream>>>(
        B_h, wt2h, wt2l, b_c2h, wt3h, wt3l, XL, N);

    // --- fused conv3 gather + conv4 GEMM: zpre = tanh(P*XL+b3) @ W4 -> B_h ---
    gather34_kernel<<<PERSIST_BLOCKS, blk, 0, stream>>>(
        XL, b_h2h, dinv, rowp, csr, wt4h, wt4l, B_h, N);

    // --- conv4 gather: z = P*zpre + b4 -> fp32 out ---
    gather_h_kernel<64, false, true, true><<<PERSIST_BLOCKS, blk, 0, stream>>>(
        B_h, b_h2l, dinv, rowp, csr, out, 64, 0, N);
}

// Round 7
// 687.362 us; speedup vs baseline: 1.0138x; 1.0138x over previous
//
#include <hip/hip_runtime.h>
#include <cmath>
#include <cstdint>

// ---------------------------------------------------------------------------
// SeparateHiddenGCAEEncoder: 4 chained GCN convs, P = D^-1/2 (A+I) D^-1/2.
// Round 14 (resubmit; round-6 bench died to container infra, not the kernel).
//  - Round-5 diagnostic exposed fill as the hidden #1 (~130us inside
//    fill_conv1: 1.0 TB/s, all pipes idle). Cause: nontemporal_store on a
//    SCATTER bypasses L2 write-combining -> 1.6M partial-line HBM write
//    transactions (79MB measured vs 38MB payload). Fix: plain store; L2
//    merges the ~16 same-row 8B writes into full-line evictions.
//  - NT kept only on coalesced streaming stores (gather outputs).
//  - everything else unchanged.
// ---------------------------------------------------------------------------

typedef _Float16 f16;
typedef _Float16 f16x8 __attribute__((ext_vector_type(8)));
typedef _Float16 f16x4 __attribute__((ext_vector_type(4)));
typedef float f32x4 __attribute__((ext_vector_type(4)));
typedef unsigned int u32x4 __attribute__((ext_vector_type(4)));
typedef unsigned int u32x2 __attribute__((ext_vector_type(2)));

constexpr int PERSIST_BLOCKS = 2048;  // 8 blocks/CU x 256 CU resident capacity

// ---------------- weight prep helper ----------------------------------------
// Fragment order for mfma_f32_16x16x32_f16 B operand: value W[k][m] lives at
//   ((k/32)*(M/16) + m/16)*512 + lane*8 + (k&7), lane = ((k>>3)&3)*16 + (m&15)
__device__ inline void wprep_one(const float* __restrict__ W, f16* __restrict__ hi,
                                 f16* __restrict__ lo, int M, int idx) {
    int k = idx / M, m = idx % M;
    float w = W[idx];
    f16 h = (f16)w;
    int f = ((k >> 5) * (M >> 4) + (m >> 4)) * 512 + (((k >> 3) & 3) << 7) + ((m & 15) << 3) + (k & 7);
    hi[f] = h;
    lo[f] = (f16)(w - (float)h);
}

// ---------------- fused prep: count+rank ∥ weight prep ∥ cond convert -------
__global__ void prep_graph_kernel(const int* __restrict__ dst, int* __restrict__ count,
                                  int* __restrict__ rank, int E, int cb,
                                  const float* __restrict__ W1, f16* h1, f16* l1,
                                  const float* __restrict__ W2, f16* h2, f16* l2,
                                  const float* __restrict__ W3, f16* h3, f16* l3,
                                  const float* __restrict__ W4, f16* h4, f16* l4,
                                  const float* __restrict__ cond, f16* __restrict__ XL, int N) {
    int b = blockIdx.x;
    int t = threadIdx.x;
    if (b < cb) {
        int e = b * 256 + t;
        if (e < E) rank[e] = atomicAdd(&count[dst[e]], 1);
    } else if (b < cb + 128) {
        wprep_one(W1, h1, l1, 128, (b - cb) * 256 + t);            // 256x128
    } else if (b < cb + 160) {
        wprep_one(W2, h2, l2, 128, (b - cb - 128) * 256 + t);      // 64x128
    } else if (b < cb + 288) {
        wprep_one(W3, h3, l3, 128, (b - cb - 160) * 256 + t);      // 256x128
    } else if (b < cb + 320) {
        wprep_one(W4, h4, l4, 64, (b - cb - 288) * 256 + t);       // 128x64
    } else {
        int i = (b - cb - 320) * 256 + t;                          // quad index
        if (i < N * 16) {
            int node = i >> 4, q = i & 15;
            float4 v = ((const float4*)cond)[i];
            union { f16 h[4]; uint2 u; } p;
            p.h[0] = (f16)v.x; p.h[1] = (f16)v.y; p.h[2] = (f16)v.z; p.h[3] = (f16)v.w;
            *(uint2*)(XL + (size_t)node * 192 + 128 + q * 4) = p.u;
        }
    }
}

constexpr int SCAN_VPT = 8;
constexpr int SCAN_TILE = 256 * SCAN_VPT;  // 2048

// partial sums + dinv (count is loaded here anyway)
__global__ __launch_bounds__(256) void scan_partial_kernel(const int* __restrict__ count,
                                                           float* __restrict__ dinv,
                                                           int* __restrict__ blocksums, int N) {
    __shared__ int red[256];
    const int t = threadIdx.x;
    int base = blockIdx.x * SCAN_TILE + t * SCAN_VPT;
    int s = 0;
#pragma unroll
    for (int i = 0; i < SCAN_VPT; ++i) {
        int idx = base + i;
        if (idx < N) {
            int c = count[idx];
            dinv[idx] = rsqrtf((float)(c + 1));  // +1 self loop
            s += c;
        }
    }
    red[t] = s;
    __syncthreads();
    for (int off = 128; off > 0; off >>= 1) {
        if (t < off) red[t] += red[t + off];
        __syncthreads();
    }
    if (t == 0) blocksums[blockIdx.x] = red[0];
}

// final scan; block-sum exclusive scan (<=64 blocks) inlined per block
__global__ __launch_bounds__(256) void scan_final_kernel(const int* __restrict__ count,
                                                         const int* __restrict__ blocksums,
                                                         int* __restrict__ row_ptr, int N, int nb) {
    __shared__ int red[256];
    __shared__ int bs[64];
    const int t = threadIdx.x;
    if (t < 64) bs[t] = (t < nb) ? blocksums[t] : 0;
    __syncthreads();
    for (int off = 1; off < 64; off <<= 1) {
        int u = (t < 64 && t >= off) ? bs[t - off] : 0;
        __syncthreads();
        if (t < 64) bs[t] += u;
        __syncthreads();
    }
    const int myBase = (blockIdx.x > 0) ? bs[blockIdx.x - 1] : 0;

    int base = blockIdx.x * SCAN_TILE + t * SCAN_VPT;
    int vals[SCAN_VPT];
    int s = 0;
#pragma unroll
    for (int i = 0; i < SCAN_VPT; ++i) {
        int idx = base + i;
        vals[i] = (idx < N) ? count[idx] : 0;
        s += vals[i];
    }
    red[t] = s;
    __syncthreads();
    for (int off = 1; off < 256; off <<= 1) {
        int u = (t >= off) ? red[t - off] : 0;
        __syncthreads();
        red[t] += u;
        __syncthreads();
    }
    int run = red[t] - s + myBase;
#pragma unroll
    for (int i = 0; i < SCAN_VPT; ++i) {
        int idx = base + i;
        if (idx < N) {
            row_ptr[idx] = run;
            run += vals[i];
            if (idx == N - 1) row_ptr[N] = run;
        }
    }
}

// ---------------- fill body (device) ----------------------------------------
__device__ inline void fill_body(int b, const int* __restrict__ src, const int* __restrict__ dst,
                                 const int* __restrict__ rank, const float* __restrict__ dinv,
                                 const int* __restrict__ row_ptr, long long* __restrict__ csr,
                                 int E) {
    int e = b * 256 + threadIdx.x;
    if (e >= E) return;
    int s = src[e];
    int d = dst[e];
    int pos = row_ptr[d] + rank[e];
    float nrm = dinv[s] * dinv[d];
    long long v = ((long long)(unsigned)__float_as_int(nrm) << 32) | (unsigned)s;
    csr[pos] = v;  // PLAIN store: scatter must go through L2 for write-combining
}

// ---------------- no-LDS direct-fragment MFMA GEMM body (conv1) -------------
template <int K, int M, bool X_IS_HALF>
__device__ inline void gemm_direct_body(
    int bid, const void* __restrict__ Xv, const f16* __restrict__ WFh,
    const f16* __restrict__ WFl, f16* __restrict__ out,
    int ld, int colOff, int ldx, int N) {
    constexpr int BM = 128;
    constexpr int SW = M / 4;
    constexpr int CT = SW / 16;
    constexpr int RT = BM / 16;
    constexpr int KS = K / 32;
    constexpr int MT = M / 16;

    const int tid = threadIdx.x;
    const int lane = tid & 63;
    const int wv = tid >> 6;
    const int m16 = lane & 15;
    const int quad = lane >> 4;
    const int row0 = bid * BM;

    int xr[RT];
#pragma unroll
    for (int rt = 0; rt < RT; ++rt) {
        int r = row0 + rt * 16 + m16;
        xr[rt] = r < N ? r : N - 1;
    }

    f32x4 acc[RT][CT];
#pragma unroll
    for (int rt = 0; rt < RT; ++rt)
#pragma unroll
        for (int ct = 0; ct < CT; ++ct) acc[rt][ct] = (f32x4){0.f, 0.f, 0.f, 0.f};

    for (int ks = 0; ks < KS; ++ks) {
        const int k0 = ks * 32;
        f16x8 bh[CT], bl[CT];
#pragma unroll
        for (int ct = 0; ct < CT; ++ct) {
            const int fb = ((ks * MT + wv * CT + ct) << 9) + lane * 8;
            bh[ct] = *(const f16x8*)(WFh + fb);
            bl[ct] = *(const f16x8*)(WFl + fb);
        }
#pragma unroll
        for (int rt = 0; rt < RT; ++rt) {
            f16x8 a;
            if (X_IS_HALF) {
                a = *(const f16x8*)((const f16*)Xv + (size_t)xr[rt] * ldx + k0 + quad * 8);
            } else {
                const float* xp = (const float*)Xv + (size_t)xr[rt] * ldx + k0 + quad * 8;
                f32x4 v0 = *(const f32x4*)xp;
                f32x4 v1 = *(const f32x4*)(xp + 4);
                a[0] = (f16)v0[0]; a[1] = (f16)v0[1]; a[2] = (f16)v0[2]; a[3] = (f16)v0[3];
                a[4] = (f16)v1[0]; a[5] = (f16)v1[1]; a[6] = (f16)v1[2]; a[7] = (f16)v1[3];
            }
#pragma unroll
            for (int ct = 0; ct < CT; ++ct) {
                acc[rt][ct] = __builtin_amdgcn_mfma_f32_16x16x32_f16(a, bh[ct], acc[rt][ct], 0, 0, 0);
                acc[rt][ct] = __builtin_amdgcn_mfma_f32_16x16x32_f16(a, bl[ct], acc[rt][ct], 0, 0, 0);
            }
        }
    }

#pragma unroll
    for (int rt = 0; rt < RT; ++rt) {
#pragma unroll
        for (int r = 0; r < 4; ++r) {
            int row = row0 + rt * 16 + quad * 4 + r;
            if (row < N) {
                f16* op = out + (size_t)row * ld + colOff + wv * SW + m16;
#pragma unroll
                for (int ct = 0; ct < CT; ++ct) op[ct * 16] = (f16)acc[rt][ct][r];
            }
        }
    }
}

// ---------------- merged: conv1 GEMM ∥ CSR fill ------------------------------
__global__ __launch_bounds__(256) void fill_conv1_kernel(
    const float* __restrict__ feature, const f16* __restrict__ W1h,
    const f16* __restrict__ W1l, f16* __restrict__ XL, int N, int gemmBlocks,
    const int* __restrict__ src, const int* __restrict__ dst,
    const int* __restrict__ rank, const float* __restrict__ dinv,
    const int* __restrict__ row_ptr, long long* __restrict__ csr, int E) {
    int b = blockIdx.x;
    if (b < gemmBlocks) {
        gemm_direct_body<256, 128, false>(b, feature, W1h, W1l, XL, 192, 0, 256, N);
    } else {
        fill_body(b - gemmBlocks, src, dst, rank, dinv, row_ptr, csr, E);
    }
}

// ---------------- fused conv2+conv3 GEMM ------------------------------------
__global__ __launch_bounds__(256) void gemm_conv23_kernel(
    const f16* __restrict__ Bh, const f16* __restrict__ W2h, const f16* __restrict__ W2l,
    const float* __restrict__ b2, const f16* __restrict__ W3h, const f16* __restrict__ W3l,
    f16* __restrict__ outXL, int N) {
    constexpr int RT = 8, CT = 2, LP = 136;
    __shared__ f16 c2s[128 * LP];

    const int tid = threadIdx.x;
    const int lane = tid & 63;
    const int wv = tid >> 6;
    const int m16 = lane & 15;
    const int quad = lane >> 4;
    const int row0 = blockIdx.x * 128;

    int xr[RT];
#pragma unroll
    for (int rt = 0; rt < RT; ++rt) {
        int r = row0 + rt * 16 + m16;
        xr[rt] = r < N ? r : N - 1;
    }

    // ---- step 1: c2h tile ----
    {
        f32x4 acc2[RT][CT];
#pragma unroll
        for (int rt = 0; rt < RT; ++rt)
#pragma unroll
            for (int ct = 0; ct < CT; ++ct) acc2[rt][ct] = (f32x4){0.f, 0.f, 0.f, 0.f};
#pragma unroll
        for (int ks = 0; ks < 2; ++ks) {
            f16x8 bh[CT], bl[CT];
#pragma unroll
            for (int ct = 0; ct < CT; ++ct) {
                const int fb = ((ks * 8 + wv * CT + ct) << 9) + lane * 8;
                bh[ct] = *(const f16x8*)(W2h + fb);
                bl[ct] = *(const f16x8*)(W2l + fb);
            }
#pragma unroll
            for (int rt = 0; rt < RT; ++rt) {
                f16x8 a = *(const f16x8*)(Bh + (size_t)xr[rt] * 256 + 128 + ks * 32 + quad * 8);
#pragma unroll
                for (int ct = 0; ct < CT; ++ct) {
                    acc2[rt][ct] = __builtin_amdgcn_mfma_f32_16x16x32_f16(a, bh[ct], acc2[rt][ct], 0, 0, 0);
                    acc2[rt][ct] = __builtin_amdgcn_mfma_f32_16x16x32_f16(a, bl[ct], acc2[rt][ct], 0, 0, 0);
                }
            }
        }
        float b2r[CT];
#pragma unroll
        for (int ct = 0; ct < CT; ++ct) b2r[ct] = b2[wv * 32 + ct * 16 + m16];
#pragma unroll
        for (int rt = 0; rt < RT; ++rt)
#pragma unroll
            for (int r = 0; r < 4; ++r) {
                int row = rt * 16 + quad * 4 + r;
#pragma unroll
                for (int ct = 0; ct < CT; ++ct)
                    c2s[row * LP + wv * 32 + ct * 16 + m16] = (f16)tanhf(acc2[rt][ct][r] + b2r[ct]);
            }
    }
    __syncthreads();

    // ---- step 2: [f2h | c2h] @ W3 ----
    f32x4 acc3[RT][CT];
#pragma unroll
    for (int rt = 0; rt < RT; ++rt)
#pragma unroll
        for (int ct = 0; ct < CT; ++ct) acc3[rt][ct] = (f32x4){0.f, 0.f, 0.f, 0.f};
#pragma unroll
    for (int ks = 0; ks < 8; ++ks) {
        f16x8 bh[CT], bl[CT];
#pragma unroll
        for (int ct = 0; ct < CT; ++ct) {
            const int fb = ((ks * 8 + wv * CT + ct) << 9) + lane * 8;
            bh[ct] = *(const f16x8*)(W3h + fb);
            bl[ct] = *(const f16x8*)(W3l + fb);
        }
#pragma unroll
        for (int rt = 0; rt < RT; ++rt) {
            f16x8 a;
            if (ks < 4) {
                a = *(const f16x8*)(Bh + (size_t)xr[rt] * 256 + ks * 32 + quad * 8);
            } else {
                a = *(const f16x8*)(&c2s[(rt * 16 + m16) * LP + (ks - 4) * 32 + quad * 8]);
            }
#pragma unroll
            for (int ct = 0; ct < CT; ++ct) {
                acc3[rt][ct] = __builtin_amdgcn_mfma_f32_16x16x32_f16(a, bh[ct], acc3[rt][ct], 0, 0, 0);
                acc3[rt][ct] = __builtin_amdgcn_mfma_f32_16x16x32_f16(a, bl[ct], acc3[rt][ct], 0, 0, 0);
            }
        }
    }

#pragma unroll
    for (int rt = 0; rt < RT; ++rt)
#pragma unroll
        for (int r = 0; r < 4; ++r) {
            int row = row0 + rt * 16 + quad * 4 + r;
            if (row < N) {
                f16* op = outXL + (size_t)row * 128 + wv * 32 + m16;
#pragma unroll
                for (int ct = 0; ct < CT; ++ct) op[ct * 16] = (f16)acc3[rt][ct][r];
            }
        }
}

// ---------------- generic f16 gather (persistent, conv4 final) --------------
template <int M, bool TANH, bool HAS_BIAS, bool OUT_F32>
__global__ __launch_bounds__(256) void gather_h_kernel(
    const f16* __restrict__ xl, const float* __restrict__ b,
    const float* __restrict__ dinv, const int* __restrict__ row_ptr,
    const long long* __restrict__ csr, void* __restrict__ outv,
    int ld, int colOff, int N) {
    constexpr int TPN = M / 8;
    const int nch = (N * TPN + 255) / 256;
    for (int c = blockIdx.x; c < nch; c += gridDim.x) {
        int gid = c * 256 + threadIdx.x;
        int node = gid / TPN;
        int t = gid % TPN;
        if (node >= N) continue;

        float di = dinv[node];
        float self = di * di;
        f16x8 x = *(const f16x8*)(xl + (size_t)node * M + t * 8);
        float acc[8];
#pragma unroll
        for (int j = 0; j < 8; ++j) acc[j] = (float)x[j] * self;
        if (HAS_BIAS) {
            float4 b0 = *(const float4*)(b + t * 8);
            float4 b1 = *(const float4*)(b + t * 8 + 4);
            acc[0] += b0.x; acc[1] += b0.y; acc[2] += b0.z; acc[3] += b0.w;
            acc[4] += b1.x; acc[5] += b1.y; acc[6] += b1.z; acc[7] += b1.w;
        }

        int p = row_ptr[node];
        const int p1 = row_ptr[node + 1];
        const int last = p1 - 1;
        long long e0 = 0, e1 = 0, e2 = 0, e3 = 0;
        if (p < p1) {
            e0 = __builtin_nontemporal_load(csr + p);
            e1 = __builtin_nontemporal_load(csr + (p + 1 < p1 ? p + 1 : last));
            e2 = __builtin_nontemporal_load(csr + (p + 2 < p1 ? p + 2 : last));
            e3 = __builtin_nontemporal_load(csr + (p + 3 < p1 ? p + 3 : last));
        }
        while (p < p1) {
            const long long c0 = e0, c1 = e1, c2 = e2, c3 = e3;
            const int pn = p + 4;
            if (pn < p1) {
                e0 = __builtin_nontemporal_load(csr + pn);
                e1 = __builtin_nontemporal_load(csr + (pn + 1 < p1 ? pn + 1 : last));
                e2 = __builtin_nontemporal_load(csr + (pn + 2 < p1 ? pn + 2 : last));
                e3 = __builtin_nontemporal_load(csr + (pn + 3 < p1 ? pn + 3 : last));
            }
            int s0 = (int)c0, s1 = (int)c1, s2 = (int)c2, s3 = (int)c3;
            float n0 = __int_as_float((int)(c0 >> 32));
            float n1 = (p + 1 < p1) ? __int_as_float((int)(c1 >> 32)) : 0.f;
            float n2 = (p + 2 < p1) ? __int_as_float((int)(c2 >> 32)) : 0.f;
            float n3 = (p + 3 < p1) ? __int_as_float((int)(c3 >> 32)) : 0.f;
            f16x8 v0 = *(const f16x8*)(xl + (size_t)s0 * M + t * 8);
            f16x8 v1 = *(const f16x8*)(xl + (size_t)s1 * M + t * 8);
            f16x8 v2 = *(const f16x8*)(xl + (size_t)s2 * M + t * 8);
            f16x8 v3 = *(const f16x8*)(xl + (size_t)s3 * M + t * 8);
#pragma unroll
            for (int j = 0; j < 8; ++j)
                acc[j] += ((float)v0[j] * n0 + (float)v1[j] * n1) +
                          ((float)v2[j] * n2 + (float)v3[j] * n3);
            p = pn;
        }

        if (TANH) {
#pragma unroll
            for (int j = 0; j < 8; ++j) acc[j] = tanhf(acc[j]);
        }

        if (OUT_F32) {
            float* op = (float*)outv + (size_t)node * ld + colOff + t * 8;
            f32x4 o0 = {acc[0], acc[1], acc[2], acc[3]};
            f32x4 o1 = {acc[4], acc[5], acc[6], acc[7]};
            __builtin_nontemporal_store(o0, (f32x4*)op);
            __builtin_nontemporal_store(o1, (f32x4*)(op + 4));
        } else {
            union { f16 h[8]; u32x4 u; } o;
#pragma unroll
            for (int j = 0; j < 8; ++j) o.h[j] = (f16)acc[j];
            __builtin_nontemporal_store(o.u, (u32x4*)((f16*)outv + (size_t)node * ld + colOff + t * 8));
        }
    }
}

// ---------------- fused conv1/conv2 gather (persistent, node range) ---------
__global__ __launch_bounds__(256) void gather_fused_kernel(
    const f16* __restrict__ XL, const float* __restrict__ bA,
    const float* __restrict__ dinv, const int* __restrict__ row_ptr,
    const long long* __restrict__ csr, f16* __restrict__ out, int n0, int n1) {
    const int nch = ((n1 - n0) * 16 + 255) / 256;
    const int t = threadIdx.x & 15;
    for (int c = blockIdx.x; c < nch; c += gridDim.x) {
        int node = n0 + ((c * 256 + threadIdx.x) >> 4);
        if (node >= n1) continue;

        float di = dinv[node];
        float self = di * di;
        const f16* base = XL + (size_t)node * 192;
        f16x8 xa = *(const f16x8*)(base + t * 8);
        f16x4 xc = *(const f16x4*)(base + 128 + t * 4);
        float accA[8], accC[4];
#pragma unroll
        for (int j = 0; j < 8; ++j) accA[j] = (float)xa[j] * self;
#pragma unroll
        for (int j = 0; j < 4; ++j) accC[j] = (float)xc[j] * self;
        {
            float4 b0 = *(const float4*)(bA + t * 8);
            float4 b1 = *(const float4*)(bA + t * 8 + 4);
            accA[0] += b0.x; accA[1] += b0.y; accA[2] += b0.z; accA[3] += b0.w;
            accA[4] += b1.x; accA[5] += b1.y; accA[6] += b1.z; accA[7] += b1.w;
        }

        int p = row_ptr[node];
        const int p1 = row_ptr[node + 1];
        const int last = p1 - 1;
        long long e0 = 0, e1 = 0, e2 = 0, e3 = 0;
        if (p < p1) {
            e0 = __builtin_nontemporal_load(csr + p);
            e1 = __builtin_nontemporal_load(csr + (p + 1 < p1 ? p + 1 : last));
            e2 = __builtin_nontemporal_load(csr + (p + 2 < p1 ? p + 2 : last));
            e3 = __builtin_nontemporal_load(csr + (p + 3 < p1 ? p + 3 : last));
        }
        while (p < p1) {
            const long long c0 = e0, c1 = e1, c2 = e2, c3 = e3;
            const int pn = p + 4;
            if (pn < p1) {
                e0 = __builtin_nontemporal_load(csr + pn);
                e1 = __builtin_nontemporal_load(csr + (pn + 1 < p1 ? pn + 1 : last));
                e2 = __builtin_nontemporal_load(csr + (pn + 2 < p1 ? pn + 2 : last));
                e3 = __builtin_nontemporal_load(csr + (pn + 3 < p1 ? pn + 3 : last));
            }
            int s0 = (int)c0, s1 = (int)c1, s2 = (int)c2, s3 = (int)c3;
            float n0f = __int_as_float((int)(c0 >> 32));
            float n1f = (p + 1 < p1) ? __int_as_float((int)(c1 >> 32)) : 0.f;
            float n2f = (p + 2 < p1) ? __int_as_float((int)(c2 >> 32)) : 0.f;
            float n3f = (p + 3 < p1) ? __int_as_float((int)(c3 >> 32)) : 0.f;
            const f16* r0 = XL + (size_t)s0 * 192;
            const f16* r1 = XL + (size_t)s1 * 192;
            const f16* r2 = XL + (size_t)s2 * 192;
            const f16* r3 = XL + (size_t)s3 * 192;
            f16x8 a0 = *(const f16x8*)(r0 + t * 8);
            f16x8 a1 = *(const f16x8*)(r1 + t * 8);
            f16x8 a2 = *(const f16x8*)(r2 + t * 8);
            f16x8 a3 = *(const f16x8*)(r3 + t * 8);
            f16x4 q0 = *(const f16x4*)(r0 + 128 + t * 4);
            f16x4 q1 = *(const f16x4*)(r1 + 128 + t * 4);
            f16x4 q2 = *(const f16x4*)(r2 + 128 + t * 4);
            f16x4 q3 = *(const f16x4*)(r3 + 128 + t * 4);
#pragma unroll
            for (int j = 0; j < 8; ++j)
                accA[j] += ((float)a0[j] * n0f + (float)a1[j] * n1f) +
                           ((float)a2[j] * n2f + (float)a3[j] * n3f);
#pragma unroll
            for (int j = 0; j < 4; ++j)
                accC[j] += ((float)q0[j] * n0f + (float)q1[j] * n1f) +
                           ((float)q2[j] * n2f + (float)q3[j] * n3f);
            p = pn;
        }

#pragma unroll
        for (int j = 0; j < 8; ++j) accA[j] = tanhf(accA[j]);

        union { f16 h[8]; u32x4 u; } oa;
#pragma unroll
        for (int j = 0; j < 8; ++j) oa.h[j] = (f16)accA[j];
        __builtin_nontemporal_store(oa.u, (u32x4*)(out + (size_t)node * 256 + t * 8));
        union { f16 h[4]; u32x2 u; } oc;
#pragma unroll
        for (int j = 0; j < 4; ++j) oc.h[j] = (f16)accC[j];
        __builtin_nontemporal_store(oc.u, (u32x2*)(out + (size_t)node * 256 + 128 + t * 4));
    }
}

// ---------------- fused conv3 gather + conv4 GEMM (persistent) --------------
__global__ __launch_bounds__(256) void gather34_kernel(
    const f16* __restrict__ xl, const float* __restrict__ b,
    const float* __restrict__ dinv, const int* __restrict__ row_ptr,
    const long long* __restrict__ csr, const f16* __restrict__ W4h,
    const f16* __restrict__ W4l, f16* __restrict__ zpre, int N) {
    constexpr int LP = 136;
    __shared__ f16 h2s[16 * LP];
    const int tid = threadIdx.x;
    const int nloc = tid >> 4;
    const int t = tid & 15;
    const int lane = tid & 63;
    const int wv = tid >> 6;
    const int m16 = lane & 15;
    const int quad = lane >> 4;
    const int nch = (N + 15) / 16;

    for (int c = blockIdx.x; c < nch; c += gridDim.x) {
        const int node = c * 16 + nloc;
        const bool active = node < N;

        float acc[8];
        if (active) {
            float di = dinv[node];
            float self = di * di;
            f16x8 x = *(const f16x8*)(xl + (size_t)node * 128 + t * 8);
#pragma unroll
            for (int j = 0; j < 8; ++j) acc[j] = (float)x[j] * self;
            {
                float4 b0 = *(const float4*)(b + t * 8);
                float4 b1 = *(const float4*)(b + t * 8 + 4);
                acc[0] += b0.x; acc[1] += b0.y; acc[2] += b0.z; acc[3] += b0.w;
                acc[4] += b1.x; acc[5] += b1.y; acc[6] += b1.z; acc[7] += b1.w;
            }

            int p = row_ptr[node];
            const int p1 = row_ptr[node + 1];
            const int last = p1 - 1;
            long long e0 = 0, e1 = 0, e2 = 0, e3 = 0;
            if (p < p1) {
                e0 = __builtin_nontemporal_load(csr + p);
                e1 = __builtin_nontemporal_load(csr + (p + 1 < p1 ? p + 1 : last));
                e2 = __builtin_nontemporal_load(csr + (p + 2 < p1 ? p + 2 : last));
                e3 = __builtin_nontemporal_load(csr + (p + 3 < p1 ? p + 3 : last));
            }
            while (p < p1) {
                const long long c0 = e0, c1 = e1, c2 = e2, c3 = e3;
                const int pn = p + 4;
                if (pn < p1) {
                    e0 = __builtin_nontemporal_load(csr + pn);
                    e1 = __builtin_nontemporal_load(csr + (pn + 1 < p1 ? pn + 1 : last));
                    e2 = __builtin_nontemporal_load(csr + (pn + 2 < p1 ? pn + 2 : last));
                    e3 = __builtin_nontemporal_load(csr + (pn + 3 < p1 ? pn + 3 : last));
                }
                int s0 = (int)c0, s1 = (int)c1, s2 = (int)c2, s3 = (int)c3;
                float n0 = __int_as_float((int)(c0 >> 32));
                float n1 = (p + 1 < p1) ? __int_as_float((int)(c1 >> 32)) : 0.f;
                float n2 = (p + 2 < p1) ? __int_as_float((int)(c2 >> 32)) : 0.f;
                float n3 = (p + 3 < p1) ? __int_as_float((int)(c3 >> 32)) : 0.f;
                f16x8 v0 = *(const f16x8*)(xl + (size_t)s0 * 128 + t * 8);
                f16x8 v1 = *(const f16x8*)(xl + (size_t)s1 * 128 + t * 8);
                f16x8 v2 = *(const f16x8*)(xl + (size_t)s2 * 128 + t * 8);
                f16x8 v3 = *(const f16x8*)(xl + (size_t)s3 * 128 + t * 8);
#pragma unroll
                for (int j = 0; j < 8; ++j)
                    acc[j] += ((float)v0[j] * n0 + (float)v1[j] * n1) +
                              ((float)v2[j] * n2 + (float)v3[j] * n3);
                p = pn;
            }

            union { f16 h[8]; u32x4 u; } o;
#pragma unroll
            for (int j = 0; j < 8; ++j) o.h[j] = (f16)tanhf(acc[j]);
            *(u32x4*)(&h2s[nloc * LP + t * 8]) = o.u;
        }
        __syncthreads();

        // mini-GEMM: zpre[16][64] = h2s[16][128] @ W4
        f32x4 a4 = (f32x4){0.f, 0.f, 0.f, 0.f};
#pragma unroll
        for (int ks = 0; ks < 4; ++ks) {
            f16x8 av = *(const f16x8*)(&h2s[m16 * LP + ks * 32 + quad * 8]);
            const int fb = ((ks * 4 + wv) << 9) + lane * 8;
            f16x8 bh = *(const f16x8*)(W4h + fb);
            f16x8 bl = *(const f16x8*)(W4l + fb);
            a4 = __builtin_amdgcn_mfma_f32_16x16x32_f16(av, bh, a4, 0, 0, 0);
            a4 = __builtin_amdgcn_mfma_f32_16x16x32_f16(av, bl, a4, 0, 0, 0);
        }
#pragma unroll
        for (int r = 0; r < 4; ++r) {
            int g = c * 16 + quad * 4 + r;
            if (g < N) zpre[(size_t)g * 64 + wv * 16 + m16] = (f16)a4[r];
        }
        __syncthreads();  // protect h2s before next chunk overwrites
    }
}

// ---------------------------------------------------------------------------
extern "C" void kernel_launch(void* const* d_in, const int* in_sizes, int n_in,
                              void* d_out, int out_size, void* d_ws, size_t ws_size,
                              hipStream_t stream) {
    const int FD = 256;

    const float* feature   = (const float*)d_in[0];
    const float* condition = (const float*)d_in[1];
    const int*   edge      = (const int*)d_in[2];
    const float* W_f2h = (const float*)d_in[3];
    const float* b_f2h = (const float*)d_in[4];
    const float* W_c2h = (const float*)d_in[5];
    const float* b_c2h = (const float*)d_in[6];
    const float* W_h2h = (const float*)d_in[7];
    const float* b_h2h = (const float*)d_in[8];
    const float* W_h2l = (const float*)d_in[9];
    const float* b_h2l = (const float*)d_in[10];
    float* out = (float*)d_out;

    const int N = in_sizes[0] / FD;   // 100000
    const int E = in_sizes[2] / 2;    // 1600000
    const int* src = edge;
    const int* dst = edge + E;

    // workspace layout
    float* ws_f   = (float*)d_ws;
    float* dinv   = ws_f;                                // N floats
    int*   count  = (int*)(ws_f + N);                    // N ints
    int*   rowp   = count + N;                           // N+1 ints
    int*   bsums  = rowp + N + 1;                        // 1024 ints
    int*   rank   = bsums + 1024;                        // E ints
    long long* csr = (long long*)(((uintptr_t)(rank + E) + 15) & ~(uintptr_t)15);  // E x 8B
    f16*   XL     = (f16*)(csr + E);                     // N*192 f16 ([xlA|cond]; reused as h@W3)
    f16*   B_h    = XL + (size_t)N * 192;                // N*256 f16 ([f2h|cprop]; reused as zpre)
    f16*   wt1h   = B_h + (size_t)N * 256;               // 128*256
    f16*   wt1l   = wt1h + 128 * 256;
    f16*   wt2h   = wt1l + 128 * 256;                    // 128*64
    f16*   wt2l   = wt2h + 128 * 64;
    f16*   wt3h   = wt2l + 128 * 64;                     // 128*256
    f16*   wt3l   = wt3h + 128 * 256;
    f16*   wt4h   = wt3l + 128 * 256;                    // 64*128
    f16*   wt4l   = wt4h + 64 * 128;

    const int TB = 256;
    dim3 blk(TB);
    const int nScanBlocks = (N + SCAN_TILE - 1) / SCAN_TILE;  // 49 (<=64 required)
    const int countBlocks = (E + TB - 1) / TB;                // 6250
    const int condBlocks  = (N * 16 + TB - 1) / TB;           // 6250
    const int gemm_grid   = (N + 127) / 128;                  // 782

    // --- fused prep: count_rank ∥ wprep ∥ cond convert ---
    hipMemsetAsync(count, 0, (size_t)N * sizeof(int), stream);
    prep_graph_kernel<<<countBlocks + 320 + condBlocks, blk, 0, stream>>>(
        dst, count, rank, E, countBlocks,
        W_f2h, wt1h, wt1l, W_c2h, wt2h, wt2l, W_h2h, wt3h, wt3l, W_h2l, wt4h, wt4l,
        condition, XL, N);

    // --- CSR scan ---
    scan_partial_kernel<<<nScanBlocks, blk, 0, stream>>>(count, dinv, bsums, N);
    scan_final_kernel<<<nScanBlocks, blk, 0, stream>>>(count, bsums, rowp, N, nScanBlocks);

    // --- conv1 GEMM ∥ CSR fill (independent; disjoint bottlenecks) ---
    fill_conv1_kernel<<<gemm_grid + countBlocks, blk, 0, stream>>>(
        feature, wt1h, wt1l, XL, N, gemm_grid,
        src, dst, rank, dinv, rowp, csr, E);

    // --- fused gather conv1+conv2 (two node-range halves) ---
    const int nHalf = N / 2;
    gather_fused_kernel<<<PERSIST_BLOCKS, blk, 0, stream>>>(
        XL, b_f2h, dinv, rowp, csr, B_h, 0, nHalf);
    gather_fused_kernel<<<PERSIST_BLOCKS, blk, 0, stream>>>(
        XL, b_f2h, dinv, rowp, csr, B_h, nHalf, N);

    // --- fused conv2+conv3 GEMM: [f2h | tanh(cprop@W2+b2)] @ W3 -> XL ---
    gemm_conv23_kernel<<<gemm_grid, blk, 0, stream>>>(
        B_h, wt2h, wt2l, b_c2h, wt3h, wt3l, XL, N);

    // --- fused conv3 gather + conv4 GEMM: zpre = tanh(P*XL+b3) @ W4 -> B_h ---
    gather34_kernel<<<PERSIST_BLOCKS, blk, 0, stream>>>(
        XL, b_h2h, dinv, rowp, csr, wt4h, wt4l, B_h, N);

    // --- conv4 gather: z = P*zpre + b4 -> fp32 out ---
    gather_h_kernel<64, false, true, true><<<PERSIST_BLOCKS, blk, 0, stream>>>(
        B_h, b_h2l, dinv, rowp, csr, out, 64, 0, N);
}